// Round 5
// baseline (3900.088 us; speedup 1.0000x reference)
//
#include <hip/hip_runtime.h>

#ifndef __has_builtin
#define __has_builtin(x) 0
#endif

__device__ __forceinline__ float fexp2(float x) {
#if __has_builtin(__builtin_amdgcn_exp2f)
    return __builtin_amdgcn_exp2f(x);   // v_exp_f32 (2^x)
#else
    return exp2f(x);
#endif
}
__device__ __forceinline__ float flog2(float x) {
#if __has_builtin(__builtin_amdgcn_logf)
    return __builtin_amdgcn_logf(x);    // v_log_f32 (log2 x)
#else
    return log2f(x);
#endif
}

#define NMAXN 128
#define DD    64
#define MAX_ITERS 500

// -1e5 * log2(e)  (NEG surrogate in log2 domain)
#define NEG2  (-144269.50408889634f)
// -(log2(e) / eps), eps = 1e-3 : logK2 = M * LKSC
#define LKSC  (-1442.6950408889634f)
// -(eps * ln2) : out = acc * OUTSC
#define OUTSC (-6.931471805599453e-4f)

struct SmemStage {
    float A[NMAXN * 33];
    float B[NMAXN * 33];
    float nA[NMAXN];
    float nB[NMAXN];
};
struct SmemSink {
    // [batch][buf][row*5 + w] -> (max,sum)
    float2 pA[2][NMAXN * 5];
    float2 pB[2][NMAXN * 5];
};
union SmemU {
    SmemStage st;
    SmemSink  sk;
};

// -------- schedule: sort by work, pair heavy(rank 511-j) with light(rank j) ----
__global__ void schedule_kernel(const int* __restrict__ sz1,
                                const int* __restrict__ sz2,
                                int* __restrict__ sched)
{
    __shared__ int keys[512];
    const int t = threadIdx.x;
    const int work = (((sz1[t] + 15) >> 4) * ((sz2[t] + 15) >> 4));
    keys[t] = (work << 16) | t;
    __syncthreads();
    for (int kk = 2; kk <= 512; kk <<= 1) {
        for (int j = kk >> 1; j > 0; j >>= 1) {
            int ixj = t ^ j;
            if (ixj > t) {
                int a = keys[t], b = keys[ixj];
                bool asc = ((t & kk) == 0);
                if ((a > b) == asc) { keys[t] = b; keys[ixj] = a; }
            }
            __syncthreads();
        }
    }
    if (t < 256)
        sched[t] = (keys[511 - t] & 0xFFFF) | ((keys[t] & 0xFFFF) << 16);
}

// -------- stage one batch: global -> LDS -> per-lane 8x8 logK2 tile ----------
__device__ __forceinline__ void build_lk(
    const float* __restrict__ x1, const float* __restrict__ x2,
    int off1, int off2, int n1, int n2,
    int tid, int rg, int W4, SmemStage* st,
    float (&lk)[8][8], float (&mpad)[8])
{
    __syncthreads();   // retire any prior readers of st
    if (tid < NMAXN) { st->nA[tid] = 0.f; st->nB[tid] = 0.f; }
#pragma unroll
    for (int r = 0; r < 8; ++r)
#pragma unroll
        for (int c = 0; c < 8; ++c) lk[r][c] = 0.f;
    __syncthreads();

    const int srow  = tid >> 1;
    const int shalf = tid & 1;
    for (int ch = 0; ch < 2; ++ch) {
        const float* p1 = x1 + (size_t)(off1 + srow) * DD + ch * 32 + shalf * 16;
        const float* p2 = x2 + (size_t)(off2 + srow) * DD + ch * 32 + shalf * 16;
        const bool ok1 = srow < n1;
        const bool ok2 = srow < n2;
        float va[16], vb[16];
#pragma unroll
        for (int q = 0; q < 4; ++q) {
            float4 t1 = ok1 ? ((const float4*)p1)[q] : make_float4(0.f, 0.f, 0.f, 0.f);
            float4 t2 = ok2 ? ((const float4*)p2)[q] : make_float4(0.f, 0.f, 0.f, 0.f);
            va[4*q+0] = t1.x; va[4*q+1] = t1.y; va[4*q+2] = t1.z; va[4*q+3] = t1.w;
            vb[4*q+0] = t2.x; vb[4*q+1] = t2.y; vb[4*q+2] = t2.z; vb[4*q+3] = t2.w;
        }
        float s1 = 0.f, s2 = 0.f;
        const int cb = shalf * 16;
#pragma unroll
        for (int q = 0; q < 16; ++q) {
            st->A[srow * 33 + cb + q] = va[q];
            st->B[srow * 33 + cb + q] = vb[q];
            s1 += va[q] * va[q];
            s2 += vb[q] * vb[q];
        }
        s1 += __shfl_xor(s1, 1);
        s2 += __shfl_xor(s2, 1);
        if (shalf == 0) { st->nA[srow] += s1; st->nB[srow] += s2; }
        __syncthreads();
#pragma unroll 2
        for (int d = 0; d < 32; ++d) {
            float av[8], bv[8];
#pragma unroll
            for (int r = 0; r < 8; ++r) av[r] = st->A[(rg + 16*r) * 33 + d];
#pragma unroll
            for (int c = 0; c < 8; ++c) bv[c] = st->B[(W4 + 16*c) * 33 + d];
#pragma unroll
            for (int r = 0; r < 8; ++r)
#pragma unroll
                for (int c = 0; c < 8; ++c)
                    lk[r][c] = fmaf(av[r], bv[c], lk[r][c]);
        }
        __syncthreads();
    }
    float rn1[8], rn2[8];
#pragma unroll
    for (int r = 0; r < 8; ++r) rn1[r] = st->nA[rg + 16*r];
#pragma unroll
    for (int c = 0; c < 8; ++c) rn2[c] = st->nB[W4 + 16*c];
#pragma unroll
    for (int r = 0; r < 8; ++r)
#pragma unroll
        for (int c = 0; c < 8; ++c) {
            float M = rn1[r] + rn2[c] - 2.f * lk[r][c];
            lk[r][c] = fmaxf(M, 0.f) * LKSC;
        }
#pragma unroll
    for (int c = 0; c < 8; ++c) mpad[c] = rn2[c] * LKSC;
}

// -------- v-phase over column strips [C0,C1): in-wave only ------------------
template<int C0, int C1>
__device__ __forceinline__ void v_cols(
    const float (&lk)[8][8], const float (&u)[8], float (&v)[8],
    int rmax, int n2, float lbvf, int W4,
    const float (&mpad)[8], float p1f, bool fold)
{
    const int NC = C1 - C0;
    float m_[NC], s_[NC];
#pragma unroll
    for (int c = 0; c < NC; ++c) m_[c] = lk[0][C0+c] + u[0];
#pragma unroll
    for (int r = 1; r < 4; ++r)
#pragma unroll
        for (int c = 0; c < NC; ++c) m_[c] = fmaxf(m_[c], lk[r][C0+c] + u[r]);
    if (rmax > 4) {
#pragma unroll
        for (int c = 0; c < NC; ++c) m_[c] = fmaxf(m_[c], lk[4][C0+c] + u[4]);
        if (rmax > 5) {
#pragma unroll
            for (int c = 0; c < NC; ++c) m_[c] = fmaxf(m_[c], lk[5][C0+c] + u[5]);
            if (rmax > 6) {
#pragma unroll
                for (int c = 0; c < NC; ++c) m_[c] = fmaxf(m_[c], lk[6][C0+c] + u[6]);
                if (rmax > 7) {
#pragma unroll
                    for (int c = 0; c < NC; ++c) m_[c] = fmaxf(m_[c], lk[7][C0+c] + u[7]);
                }
            }
        }
    }
#pragma unroll
    for (int c = 0; c < NC; ++c) {
        m_[c] = fmaxf(m_[c], __shfl_xor(m_[c], 4));
        m_[c] = fmaxf(m_[c], __shfl_xor(m_[c], 8));
        m_[c] = fmaxf(m_[c], __shfl_xor(m_[c], 16));
        m_[c] = fmaxf(m_[c], __shfl_xor(m_[c], 32));
    }
#pragma unroll
    for (int c = 0; c < NC; ++c)
        s_[c] = fexp2(lk[0][C0+c] + u[0] - m_[c]) + fexp2(lk[1][C0+c] + u[1] - m_[c])
              + fexp2(lk[2][C0+c] + u[2] - m_[c]) + fexp2(lk[3][C0+c] + u[3] - m_[c]);
    if (rmax > 4) {
#pragma unroll
        for (int c = 0; c < NC; ++c) s_[c] += fexp2(lk[4][C0+c] + u[4] - m_[c]);
        if (rmax > 5) {
#pragma unroll
            for (int c = 0; c < NC; ++c) s_[c] += fexp2(lk[5][C0+c] + u[5] - m_[c]);
            if (rmax > 6) {
#pragma unroll
                for (int c = 0; c < NC; ++c) s_[c] += fexp2(lk[6][C0+c] + u[6] - m_[c]);
                if (rmax > 7) {
#pragma unroll
                    for (int c = 0; c < NC; ++c) s_[c] += fexp2(lk[7][C0+c] + u[7] - m_[c]);
                }
            }
        }
    }
#pragma unroll
    for (int c = 0; c < NC; ++c) {
        s_[c] += __shfl_xor(s_[c], 4);
        s_[c] += __shfl_xor(s_[c], 8);
        s_[c] += __shfl_xor(s_[c], 16);
        s_[c] += __shfl_xor(s_[c], 32);
    }
    if (fold) {   // iter-0 analytic fold of non-materialized zero pad rows (u=0)
#pragma unroll
        for (int c = 0; c < NC; ++c) {
            float mm = fmaxf(m_[c], mpad[C0+c]);
            s_[c] = s_[c] * fexp2(m_[c] - mm) + p1f * fexp2(mpad[C0+c] - mm);
            m_[c] = mm;
        }
    }
#pragma unroll
    for (int c = 0; c < NC; ++c)
        v[C0+c] = (((W4 + 16*(C0+c)) < n2) ? lbvf : NEG2) - (m_[c] + flog2(s_[c]));
}

// -------- u-phase partials over row strips [R0_,R0_+NR) ---------------------
template<int R0_, int NR>
__device__ __forceinline__ void u_rows(
    const float (&lk)[8][8], const float (&v)[8],
    int cmax, int rg, int cg, int w, float2* __restrict__ pb)
{
    float m_[NR], s_[NR];
#pragma unroll
    for (int r = 0; r < NR; ++r) m_[r] = lk[R0_+r][0] + v[0];
#pragma unroll
    for (int c = 1; c < 4; ++c)
#pragma unroll
        for (int r = 0; r < NR; ++r) m_[r] = fmaxf(m_[r], lk[R0_+r][c] + v[c]);
    if (cmax > 4) {
#pragma unroll
        for (int r = 0; r < NR; ++r) m_[r] = fmaxf(m_[r], lk[R0_+r][4] + v[4]);
        if (cmax > 5) {
#pragma unroll
            for (int r = 0; r < NR; ++r) m_[r] = fmaxf(m_[r], lk[R0_+r][5] + v[5]);
            if (cmax > 6) {
#pragma unroll
                for (int r = 0; r < NR; ++r) m_[r] = fmaxf(m_[r], lk[R0_+r][6] + v[6]);
                if (cmax > 7) {
#pragma unroll
                    for (int r = 0; r < NR; ++r) m_[r] = fmaxf(m_[r], lk[R0_+r][7] + v[7]);
                }
            }
        }
    }
#pragma unroll
    for (int r = 0; r < NR; ++r) {
        m_[r] = fmaxf(m_[r], __shfl_xor(m_[r], 1));
        m_[r] = fmaxf(m_[r], __shfl_xor(m_[r], 2));
    }
#pragma unroll
    for (int r = 0; r < NR; ++r)
        s_[r] = fexp2(lk[R0_+r][0] + v[0] - m_[r]) + fexp2(lk[R0_+r][1] + v[1] - m_[r])
              + fexp2(lk[R0_+r][2] + v[2] - m_[r]) + fexp2(lk[R0_+r][3] + v[3] - m_[r]);
    if (cmax > 4) {
#pragma unroll
        for (int r = 0; r < NR; ++r) s_[r] += fexp2(lk[R0_+r][4] + v[4] - m_[r]);
        if (cmax > 5) {
#pragma unroll
            for (int r = 0; r < NR; ++r) s_[r] += fexp2(lk[R0_+r][5] + v[5] - m_[r]);
            if (cmax > 6) {
#pragma unroll
                for (int r = 0; r < NR; ++r) s_[r] += fexp2(lk[R0_+r][6] + v[6] - m_[r]);
                if (cmax > 7) {
#pragma unroll
                    for (int r = 0; r < NR; ++r) s_[r] += fexp2(lk[R0_+r][7] + v[7] - m_[r]);
                }
            }
        }
    }
#pragma unroll
    for (int r = 0; r < NR; ++r) {
        s_[r] += __shfl_xor(s_[r], 1);
        s_[r] += __shfl_xor(s_[r], 2);
    }
#pragma unroll
    for (int r = 0; r < NR; ++r)
        if (cg == ((R0_+r) & 3))
            pb[(rg + 16*(R0_+r)) * 5 + w] = make_float2(m_[r], s_[r]);
}

// -------- combine 4 wave-partials -> u over row strips ----------------------
template<int R0_, int NR>
__device__ __forceinline__ void c_rows(
    float (&u)[8], const float2* __restrict__ pb, int rg, int n1)
{
#pragma unroll
    for (int r = 0; r < NR; ++r) {
        const float2* pr = pb + (rg + 16*(R0_+r)) * 5;
        float2 p0 = pr[0], p1 = pr[1], p2 = pr[2], p3 = pr[3];
        float m_ = fmaxf(fmaxf(p0.x, p1.x), fmaxf(p2.x, p3.x));
        float s_ = p0.y * fexp2(p0.x - m_);
        s_ = fmaf(p1.y, fexp2(p1.x - m_), s_);
        s_ = fmaf(p2.y, fexp2(p2.x - m_), s_);
        s_ = fmaf(p3.y, fexp2(p3.x - m_), s_);
        u[R0_+r] = (((rg + 16*(R0_+r)) < n1) ? 0.f : NEG2) - (m_ + flog2(s_));
    }
}

// -------- epilogue over row strips ------------------------------------------
template<int R0_, int NR>
__device__ __forceinline__ void e_rows(
    const float (&lk)[8][8], const float (&u)[8], const float (&v)[8],
    int cmax, float& acc)
{
#pragma unroll
    for (int r = 0; r < NR; ++r) {
#pragma unroll
        for (int c = 0; c < 4; ++c)
            acc += lk[R0_+r][c] * fexp2(lk[R0_+r][c] + u[R0_+r] + v[c]);
        if (cmax > 4) { acc += lk[R0_+r][4] * fexp2(lk[R0_+r][4] + u[R0_+r] + v[4]);
        if (cmax > 5) { acc += lk[R0_+r][5] * fexp2(lk[R0_+r][5] + u[R0_+r] + v[5]);
        if (cmax > 6) { acc += lk[R0_+r][6] * fexp2(lk[R0_+r][6] + u[R0_+r] + v[6]);
        if (cmax > 7) { acc += lk[R0_+r][7] * fexp2(lk[R0_+r][7] + u[R0_+r] + v[7]); }}}}
    }
}

__global__ __launch_bounds__(256, 1)
void wasserstein_kernel(const float* __restrict__ x1, const float* __restrict__ x2,
                        const int* __restrict__ sz1, const int* __restrict__ sz2,
                        const int* __restrict__ sched,
                        float* __restrict__ out)
{
    __shared__ SmemU  sm;
    __shared__ int    soff[16];
    __shared__ float  swredA[4], swredB[4];

    const int pr   = sched[blockIdx.x];
    const int bA   = pr & 0xFFFF;        // heavy
    const int bB   = pr >> 16;           // light
    const int tid  = threadIdx.x;
    const int w    = tid >> 6;
    const int lane = tid & 63;
    const int rg   = lane >> 2;          // rows rg + 16r
    const int cg   = lane & 3;           // cols w*4+cg + 16c
    const int W4   = (w << 2) | cg;

    // ---- offsets for both batches in one scan ----
    int a1A = 0, a2A = 0, a1B = 0, a2B = 0;
#pragma unroll
    for (int q = 0; q < 2; ++q) {
        int k = tid + (q << 8);
        int s1 = sz1[k], s2 = sz2[k];
        if (k < bA) { a1A += s1; a2A += s2; }
        if (k < bB) { a1B += s1; a2B += s2; }
    }
#pragma unroll
    for (int d = 1; d < 64; d <<= 1) {
        a1A += __shfl_xor(a1A, d); a2A += __shfl_xor(a2A, d);
        a1B += __shfl_xor(a1B, d); a2B += __shfl_xor(a2B, d);
    }
    if (lane == 0) { soff[w] = a1A; soff[4+w] = a2A; soff[8+w] = a1B; soff[12+w] = a2B; }
    __syncthreads();
    const int off1A = soff[0] + soff[1] + soff[2]  + soff[3];
    const int off2A = soff[4] + soff[5] + soff[6]  + soff[7];
    const int off1B = soff[8] + soff[9] + soff[10] + soff[11];
    const int off2B = soff[12] + soff[13] + soff[14] + soff[15];
    const int n1A = sz1[bA], n2A = sz2[bA];
    const int n1B = sz1[bB], n2B = sz2[bB];
    const int rmaxA = (n1A + 15) >> 4, cmaxA = (n2A + 15) >> 4;
    const int rmaxB = (n1B + 15) >> 4, cmaxB = (n2B + 15) >> 4;

    float lkA[8][8], lkB[8][8], mpadA[8], mpadB[8];
    build_lk(x1, x2, off1A, off2A, n1A, n2A, tid, rg, W4, &sm.st, lkA, mpadA);
    build_lk(x1, x2, off1B, off2B, n1B, n2B, tid, rg, W4, &sm.st, lkB, mpadB);

    const float lbvA = flog2((float)n1A) - flog2((float)n2A);
    const float lbvB = flog2((float)n1B) - flog2((float)n2B);
    const float p1fA = (float)(NMAXN - 16 * rmaxA);
    const float p1fB = (float)(NMAXN - 16 * rmaxB);

    float uA[8], vA[8], uB[8], vB[8];
#pragma unroll
    for (int r = 0; r < 8; ++r) { uA[r] = 0.f; uB[r] = 0.f; }
    __syncthreads();   // retire staging view of the union

    for (int k = 0; k < MAX_ITERS; ++k) {
        const bool foldA = (k == 0) && (p1fA > 0.5f);
        const bool foldB = (k == 0) && (p1fB > 0.5f);

        // ===== V phases (in-wave) =====
        v_cols<0,4>(lkA, uA, vA, rmaxA, n2A, lbvA, W4, mpadA, p1fA, foldA);
        v_cols<0,4>(lkB, uB, vB, rmaxB, n2B, lbvB, W4, mpadB, p1fB, foldB);
        if (cmaxA > 4) { v_cols<4,5>(lkA, uA, vA, rmaxA, n2A, lbvA, W4, mpadA, p1fA, foldA);
        if (cmaxA > 5) { v_cols<5,6>(lkA, uA, vA, rmaxA, n2A, lbvA, W4, mpadA, p1fA, foldA);
        if (cmaxA > 6) { v_cols<6,7>(lkA, uA, vA, rmaxA, n2A, lbvA, W4, mpadA, p1fA, foldA);
        if (cmaxA > 7) { v_cols<7,8>(lkA, uA, vA, rmaxA, n2A, lbvA, W4, mpadA, p1fA, foldA); }}}}
        if (cmaxB > 4) { v_cols<4,5>(lkB, uB, vB, rmaxB, n2B, lbvB, W4, mpadB, p1fB, foldB);
        if (cmaxB > 5) { v_cols<5,6>(lkB, uB, vB, rmaxB, n2B, lbvB, W4, mpadB, p1fB, foldB);
        if (cmaxB > 6) { v_cols<6,7>(lkB, uB, vB, rmaxB, n2B, lbvB, W4, mpadB, p1fB, foldB);
        if (cmaxB > 7) { v_cols<7,8>(lkB, uB, vB, rmaxB, n2B, lbvB, W4, mpadB, p1fB, foldB); }}}}

        // ===== U phases: partials =====
        float2* pbA = sm.sk.pA[k & 1];
        float2* pbB = sm.sk.pB[k & 1];
        u_rows<0,4>(lkA, vA, cmaxA, rg, cg, w, pbA);
        if (rmaxA > 4) { u_rows<4,1>(lkA, vA, cmaxA, rg, cg, w, pbA);
        if (rmaxA > 5) { u_rows<5,1>(lkA, vA, cmaxA, rg, cg, w, pbA);
        if (rmaxA > 6) { u_rows<6,1>(lkA, vA, cmaxA, rg, cg, w, pbA);
        if (rmaxA > 7) { u_rows<7,1>(lkA, vA, cmaxA, rg, cg, w, pbA); }}}}
        u_rows<0,4>(lkB, vB, cmaxB, rg, cg, w, pbB);
        if (rmaxB > 4) { u_rows<4,1>(lkB, vB, cmaxB, rg, cg, w, pbB);
        if (rmaxB > 5) { u_rows<5,1>(lkB, vB, cmaxB, rg, cg, w, pbB);
        if (rmaxB > 6) { u_rows<6,1>(lkB, vB, cmaxB, rg, cg, w, pbB);
        if (rmaxB > 7) { u_rows<7,1>(lkB, vB, cmaxB, rg, cg, w, pbB); }}}}

        __syncthreads();   // the ONLY barrier per iteration (serves both batches)

        c_rows<0,4>(uA, pbA, rg, n1A);
        if (rmaxA > 4) { c_rows<4,1>(uA, pbA, rg, n1A);
        if (rmaxA > 5) { c_rows<5,1>(uA, pbA, rg, n1A);
        if (rmaxA > 6) { c_rows<6,1>(uA, pbA, rg, n1A);
        if (rmaxA > 7) { c_rows<7,1>(uA, pbA, rg, n1A); }}}}
        c_rows<0,4>(uB, pbB, rg, n1B);
        if (rmaxB > 4) { c_rows<4,1>(uB, pbB, rg, n1B);
        if (rmaxB > 5) { c_rows<5,1>(uB, pbB, rg, n1B);
        if (rmaxB > 6) { c_rows<6,1>(uB, pbB, rg, n1B);
        if (rmaxB > 7) { c_rows<7,1>(uB, pbB, rg, n1B); }}}}
    }

    // ---- epilogues ----
    float accA = 0.f, accB = 0.f;
    e_rows<0,4>(lkA, uA, vA, cmaxA, accA);
    if (rmaxA > 4) { e_rows<4,1>(lkA, uA, vA, cmaxA, accA);
    if (rmaxA > 5) { e_rows<5,1>(lkA, uA, vA, cmaxA, accA);
    if (rmaxA > 6) { e_rows<6,1>(lkA, uA, vA, cmaxA, accA);
    if (rmaxA > 7) { e_rows<7,1>(lkA, uA, vA, cmaxA, accA); }}}}
    e_rows<0,4>(lkB, uB, vB, cmaxB, accB);
    if (rmaxB > 4) { e_rows<4,1>(lkB, uB, vB, cmaxB, accB);
    if (rmaxB > 5) { e_rows<5,1>(lkB, uB, vB, cmaxB, accB);
    if (rmaxB > 6) { e_rows<6,1>(lkB, uB, vB, cmaxB, accB);
    if (rmaxB > 7) { e_rows<7,1>(lkB, uB, vB, cmaxB, accB); }}}}
#pragma unroll
    for (int d = 1; d < 64; d <<= 1) {
        accA += __shfl_xor(accA, d);
        accB += __shfl_xor(accB, d);
    }
    if (lane == 0) { swredA[w] = accA; swredB[w] = accB; }
    __syncthreads();
    if (tid == 0) {
        out[bA] = (swredA[0] + swredA[1] + swredA[2] + swredA[3]) * OUTSC;
        out[bB] = (swredB[0] + swredB[1] + swredB[2] + swredB[3]) * OUTSC;
    }
}

extern "C" void kernel_launch(void* const* d_in, const int* in_sizes, int n_in,
                              void* d_out, int out_size, void* d_ws, size_t ws_size,
                              hipStream_t stream) {
    const float* x1  = (const float*)d_in[0];
    const float* x2  = (const float*)d_in[1];
    const int*   sz1 = (const int*)d_in[2];
    const int*   sz2 = (const int*)d_in[3];
    float* out  = (float*)d_out;
    int* sched  = (int*)d_ws;
    hipLaunchKernelGGL(schedule_kernel, dim3(1), dim3(512), 0, stream, sz1, sz2, sched);
    hipLaunchKernelGGL(wasserstein_kernel, dim3(256), dim3(256), 0, stream,
                       x1, x2, sz1, sz2, sched, out);
}

// Round 6
// 2132.009 us; speedup vs baseline: 1.8293x; 1.8293x over previous
//
#include <hip/hip_runtime.h>

#ifndef __has_builtin
#define __has_builtin(x) 0
#endif

__device__ __forceinline__ float fexp2(float x) {
#if __has_builtin(__builtin_amdgcn_exp2f)
    return __builtin_amdgcn_exp2f(x);   // v_exp_f32 (2^x)
#else
    return exp2f(x);
#endif
}
__device__ __forceinline__ float flog2(float x) {
#if __has_builtin(__builtin_amdgcn_logf)
    return __builtin_amdgcn_logf(x);    // v_log_f32 (log2 x)
#else
    return log2f(x);
#endif
}

#define NMAXN 128
#define DD    64
#define MAX_ITERS 500

// -1e5 * log2(e)  (NEG surrogate in log2 domain)
#define NEG2  (-144269.50408889634f)
// -(log2(e) / eps), eps = 1e-3 : logK2 = M * LKSC
#define LKSC  (-1442.6950408889634f)
// -(eps * ln2) : out = acc * OUTSC
#define OUTSC (-6.931471805599453e-4f)

// s_getreg encoding: id | (offset<<6) | ((size-1)<<11)
#define GETREG_ENC(id, off, sz) ((id) | ((off) << 6) | (((sz) - 1) << 11))

struct SmemStage {
    float A[NMAXN * 33];   // set1 chunk [128][32] padded
    float B[NMAXN * 33];   // set2 chunk
    float nA[NMAXN];       // row norms set1
    float nB[NMAXN];       // row norms set2
};
struct SmemSink {
    // [buf][row*5 + w] -> (max,sum)
    float2 part[2][NMAXN * 5];
};
union SmemU {
    SmemStage st;
    SmemSink  sk;
    // occupancy clamp: 56320 B forces exactly 2 blocks/CU (160 KiB / 56.3 KiB)
    // so 512 blocks -> exactly 2 resident per CU, placement-independent.
    float force[14080];
};

// ws layout (ints): [0..511] sched desc-by-work | [512] top | [513] bot
//                   [1024..3071] per-CU role counters
__global__ void schedule_kernel(const int* __restrict__ sz1,
                                const int* __restrict__ sz2,
                                int* __restrict__ ws)
{
    __shared__ int keys[512];
    const int t = threadIdx.x;
    // zero counters region [512, 3072)
    for (int i = t; i < 2560; i += 512) ws[512 + i] = 0;
    const int work = ((sz1[t] + 15) >> 4) * ((sz2[t] + 15) >> 4);   // 16..64
    keys[t] = (work << 16) | t;
    __syncthreads();
    for (int kk = 2; kk <= 512; kk <<= 1) {
        for (int j = kk >> 1; j > 0; j >>= 1) {
            int ixj = t ^ j;
            if (ixj > t) {
                int a = keys[t], b = keys[ixj];
                bool asc = ((t & kk) == 0);
                if ((a > b) == asc) { keys[t] = b; keys[ixj] = a; }
            }
            __syncthreads();
        }
    }
    ws[t] = keys[511 - t] & 0xFFFF;   // descending by work
}

// ---------------- Sinkhorn core, templated on col strip count -------------
template<int CMAX>
__device__ __forceinline__ void run_core(
    float (&lk)[8][8], const float (&la)[8], const float (&lb)[8],
    const float (&mpad)[8], float p1f, int rmax,
    int rg, int cg, int w, int tid,
    SmemU* smu, float* swred, float* out, int outb)
{
    float u[8], v[8];
#pragma unroll
    for (int r = 0; r < 8; ++r) u[r] = 0.f;

    for (int k = 0; k < MAX_ITERS; ++k) {
        // ===== phase V: v_j = lb_j - lse_r(lk[r][j] + u[r]) (in-wave) =====
        float mx[CMAX], sc[CMAX];
#pragma unroll
        for (int c = 0; c < CMAX; ++c) mx[c] = lk[0][c] + u[0];
#pragma unroll
        for (int r = 1; r < 4; ++r)
#pragma unroll
            for (int c = 0; c < CMAX; ++c)
                mx[c] = fmaxf(mx[c], lk[r][c] + u[r]);
        if (rmax > 4) {
#pragma unroll
            for (int c = 0; c < CMAX; ++c) mx[c] = fmaxf(mx[c], lk[4][c] + u[4]);
            if (rmax > 5) {
#pragma unroll
                for (int c = 0; c < CMAX; ++c) mx[c] = fmaxf(mx[c], lk[5][c] + u[5]);
                if (rmax > 6) {
#pragma unroll
                    for (int c = 0; c < CMAX; ++c) mx[c] = fmaxf(mx[c], lk[6][c] + u[6]);
                    if (rmax > 7) {
#pragma unroll
                        for (int c = 0; c < CMAX; ++c) mx[c] = fmaxf(mx[c], lk[7][c] + u[7]);
                    }
                }
            }
        }
#pragma unroll
        for (int c = 0; c < CMAX; ++c) {   // reduce over 16 row-groups
            mx[c] = fmaxf(mx[c], __shfl_xor(mx[c], 4));
            mx[c] = fmaxf(mx[c], __shfl_xor(mx[c], 8));
            mx[c] = fmaxf(mx[c], __shfl_xor(mx[c], 16));
            mx[c] = fmaxf(mx[c], __shfl_xor(mx[c], 32));
        }
#pragma unroll
        for (int c = 0; c < CMAX; ++c) sc[c] = fexp2(lk[0][c] + u[0] - mx[c]);
#pragma unroll
        for (int r = 1; r < 4; ++r)
#pragma unroll
            for (int c = 0; c < CMAX; ++c)
                sc[c] += fexp2(lk[r][c] + u[r] - mx[c]);
        if (rmax > 4) {
#pragma unroll
            for (int c = 0; c < CMAX; ++c) sc[c] += fexp2(lk[4][c] + u[4] - mx[c]);
            if (rmax > 5) {
#pragma unroll
                for (int c = 0; c < CMAX; ++c) sc[c] += fexp2(lk[5][c] + u[5] - mx[c]);
                if (rmax > 6) {
#pragma unroll
                    for (int c = 0; c < CMAX; ++c) sc[c] += fexp2(lk[6][c] + u[6] - mx[c]);
                    if (rmax > 7) {
#pragma unroll
                        for (int c = 0; c < CMAX; ++c) sc[c] += fexp2(lk[7][c] + u[7] - mx[c]);
                    }
                }
            }
        }
#pragma unroll
        for (int c = 0; c < CMAX; ++c) {
            sc[c] += __shfl_xor(sc[c], 4);
            sc[c] += __shfl_xor(sc[c], 8);
            sc[c] += __shfl_xor(sc[c], 16);
            sc[c] += __shfl_xor(sc[c], 32);
        }
        if (k == 0 && p1f > 0.5f) {
            // analytic fold of the (128-16*rmax) non-materialized pad rows
#pragma unroll
            for (int c = 0; c < CMAX; ++c) {
                float mm = fmaxf(mx[c], mpad[c]);
                sc[c] = sc[c] * fexp2(mx[c] - mm) + p1f * fexp2(mpad[c] - mm);
                mx[c] = mm;
            }
        }
#pragma unroll
        for (int c = 0; c < CMAX; ++c)
            v[c] = lb[c] - (mx[c] + flog2(sc[c]));

        // ===== phase U: u_r = la_r - lse_c(lk[r][c] + v[c]) =====
        float mr[8], sr[8];
#define U_STRIP(r)                                                          \
        {                                                                   \
            float m_ = lk[r][0] + v[0];                                     \
            _Pragma("unroll")                                               \
            for (int c = 1; c < CMAX; ++c) m_ = fmaxf(m_, lk[r][c] + v[c]); \
            m_ = fmaxf(m_, __shfl_xor(m_, 1));                              \
            m_ = fmaxf(m_, __shfl_xor(m_, 2));                              \
            float s_ = fexp2(lk[r][0] + v[0] - m_);                         \
            _Pragma("unroll")                                               \
            for (int c = 1; c < CMAX; ++c) s_ += fexp2(lk[r][c] + v[c] - m_);\
            s_ += __shfl_xor(s_, 1);                                        \
            s_ += __shfl_xor(s_, 2);                                        \
            mr[r] = m_; sr[r] = s_;                                         \
        }
        U_STRIP(0) U_STRIP(1) U_STRIP(2) U_STRIP(3)
        if (rmax > 4) { U_STRIP(4)
            if (rmax > 5) { U_STRIP(5)
                if (rmax > 6) { U_STRIP(6)
                    if (rmax > 7) { U_STRIP(7) } } } }
#undef U_STRIP

        float2* pb = smu->sk.part[k & 1];
        pb[(rg + 16 * cg) * 5 + w] = make_float2(mr[cg], sr[cg]);
        if (cg + 4 < rmax)
            pb[(rg + 16 * (cg + 4)) * 5 + w] = make_float2(mr[cg + 4], sr[cg + 4]);
        __syncthreads();   // the ONLY barrier per iteration

#define C_STRIP(r)                                                          \
        {                                                                   \
            const float2* pr = &pb[(rg + 16 * (r)) * 5];                    \
            float2 p0 = pr[0], p1 = pr[1], p2 = pr[2], p3 = pr[3];          \
            float m_ = fmaxf(fmaxf(p0.x, p1.x), fmaxf(p2.x, p3.x));         \
            float s_ = p0.y * fexp2(p0.x - m_);                             \
            s_ = fmaf(p1.y, fexp2(p1.x - m_), s_);                          \
            s_ = fmaf(p2.y, fexp2(p2.x - m_), s_);                          \
            s_ = fmaf(p3.y, fexp2(p3.x - m_), s_);                          \
            u[r] = la[r] - (m_ + flog2(s_));                                \
        }
        C_STRIP(0) C_STRIP(1) C_STRIP(2) C_STRIP(3)
        if (rmax > 4) { C_STRIP(4)
            if (rmax > 5) { C_STRIP(5)
                if (rmax > 6) { C_STRIP(6)
                    if (rmax > 7) { C_STRIP(7) } } } }
#undef C_STRIP
    }

    // ---- epilogue: out = OUTSC * sum lk * 2^(lk+u+v) over valid slots ----
    float acc = 0.f;
#define E_STRIP(r)                                                          \
        _Pragma("unroll")                                                   \
        for (int c = 0; c < CMAX; ++c)                                      \
            acc += lk[r][c] * fexp2(lk[r][c] + u[r] + v[c]);
    E_STRIP(0) E_STRIP(1) E_STRIP(2) E_STRIP(3)
    if (rmax > 4) { E_STRIP(4)
        if (rmax > 5) { E_STRIP(5)
            if (rmax > 6) { E_STRIP(6)
                if (rmax > 7) { E_STRIP(7) } } } }
#undef E_STRIP
#pragma unroll
    for (int d = 1; d < 64; d <<= 1) acc += __shfl_xor(acc, d);
    if ((tid & 63) == 0) swred[w] = acc;
    __syncthreads();
    if (tid == 0) out[outb] = (swred[0] + swred[1] + swred[2] + swred[3]) * OUTSC;
}

__global__ __launch_bounds__(256, 2)
void wasserstein_kernel(const float* __restrict__ x1, const float* __restrict__ x2,
                        const int* __restrict__ sz1, const int* __restrict__ sz2,
                        int* __restrict__ ws,
                        float* __restrict__ out)
{
    __shared__ SmemU sm;
    __shared__ int   soff[8];
    __shared__ float swred[4];
    __shared__ int   sb;

    const int tid  = threadIdx.x;
    const int w    = tid >> 6;        // wave 0..3
    const int lane = tid & 63;
    const int rg   = lane >> 2;       // 0..15: rows rg + 16*r
    const int cg   = lane & 3;        // 0..3 : cols w*4+cg + 16*c
    const int W4   = (w << 2) | cg;   // 0..15

    // ---- placement-aware batch grab: role 0 on a CU -> heavy end, else light
    if (tid == 0) {
#if __has_builtin(__builtin_amdgcn_s_getreg)
        unsigned hw  = __builtin_amdgcn_s_getreg(GETREG_ENC(4, 0, 32));   // HW_ID
        unsigned xcc = __builtin_amdgcn_s_getreg(GETREG_ENC(20, 0, 32));  // XCC_ID
        unsigned key = ((xcc & 7u) << 8) | ((hw >> 8) & 255u);            // SE|SH|CU
#else
        unsigned key = (unsigned)(blockIdx.x & 2047);
#endif
        int role = atomicAdd(&ws[1024 + (key & 2047)], 1);
        int slot;
        if (role == 0) slot = atomicAdd(&ws[512], 1);          // 0,1,2,... heavy
        else           slot = 511 - atomicAdd(&ws[513], 1);    // 511,510,... light
        sb = ws[slot];
    }
    __syncthreads();
    const int b = sb;

    // ---- exclusive prefix sums of sizes (ragged offsets) ----
    int a1 = 0, a2 = 0;
    for (int kk = tid; kk < b; kk += 256) { a1 += sz1[kk]; a2 += sz2[kk]; }
#pragma unroll
    for (int d = 1; d < 64; d <<= 1) {
        a1 += __shfl_xor(a1, d);
        a2 += __shfl_xor(a2, d);
    }
    if (lane == 0) { soff[w] = a1; soff[4 + w] = a2; }
    if (tid < NMAXN) { sm.st.nA[tid] = 0.f; sm.st.nB[tid] = 0.f; }
    __syncthreads();
    const int off1 = soff[0] + soff[1] + soff[2] + soff[3];
    const int off2 = soff[4] + soff[5] + soff[6] + soff[7];
    const int n1 = sz1[b];
    const int n2 = sz2[b];
    const int rmax = (n1 + 15) >> 4;   // 4..8
    const int cmax = (n2 + 15) >> 4;   // 4..8

    // ---- stage sets in D-chunks of 32, accumulate dots + norms ----
    float lk[8][8];
#pragma unroll
    for (int r = 0; r < 8; ++r)
#pragma unroll
        for (int c = 0; c < 8; ++c) lk[r][c] = 0.f;

    const int srow  = tid >> 1;  // 0..127
    const int shalf = tid & 1;   // 16-float half of chunk

    for (int ch = 0; ch < 2; ++ch) {
        const float* p1 = x1 + (size_t)(off1 + srow) * DD + ch * 32 + shalf * 16;
        const float* p2 = x2 + (size_t)(off2 + srow) * DD + ch * 32 + shalf * 16;
        const bool ok1 = srow < n1;
        const bool ok2 = srow < n2;
        float va[16], vb[16];
#pragma unroll
        for (int q = 0; q < 4; ++q) {
            float4 t1 = ok1 ? ((const float4*)p1)[q] : make_float4(0.f, 0.f, 0.f, 0.f);
            float4 t2 = ok2 ? ((const float4*)p2)[q] : make_float4(0.f, 0.f, 0.f, 0.f);
            va[4*q+0] = t1.x; va[4*q+1] = t1.y; va[4*q+2] = t1.z; va[4*q+3] = t1.w;
            vb[4*q+0] = t2.x; vb[4*q+1] = t2.y; vb[4*q+2] = t2.z; vb[4*q+3] = t2.w;
        }
        float s1 = 0.f, s2 = 0.f;
        const int cb = shalf * 16;
#pragma unroll
        for (int q = 0; q < 16; ++q) {
            sm.st.A[srow * 33 + cb + q] = va[q];
            sm.st.B[srow * 33 + cb + q] = vb[q];
            s1 += va[q] * va[q];
            s2 += vb[q] * vb[q];
        }
        s1 += __shfl_xor(s1, 1);
        s2 += __shfl_xor(s2, 1);
        if (shalf == 0) { sm.st.nA[srow] += s1; sm.st.nB[srow] += s2; }
        __syncthreads();
#pragma unroll 2
        for (int d = 0; d < 32; ++d) {
            float av[8], bv[8];
#pragma unroll
            for (int r = 0; r < 8; ++r) av[r] = sm.st.A[(rg + 16*r) * 33 + d];
#pragma unroll
            for (int c = 0; c < 8; ++c) bv[c] = sm.st.B[(W4 + 16*c) * 33 + d];
#pragma unroll
            for (int r = 0; r < 8; ++r)
#pragma unroll
                for (int c = 0; c < 8; ++c)
                    lk[r][c] = fmaf(av[r], bv[c], lk[r][c]);
        }
        __syncthreads();
    }

    // logK2 = -M*log2e/eps, M = ||a||^2+||b||^2-2ab (clamped), + pad/mask data
    float la[8], lb[8], mpad[8];
    const float lbv = flog2((float)n1) - flog2((float)n2);
    {
        float rn1[8], rn2[8];
#pragma unroll
        for (int r = 0; r < 8; ++r) rn1[r] = sm.st.nA[rg + 16*r];
#pragma unroll
        for (int c = 0; c < 8; ++c) rn2[c] = sm.st.nB[W4 + 16*c];
#pragma unroll
        for (int r = 0; r < 8; ++r)
#pragma unroll
            for (int c = 0; c < 8; ++c) {
                float M = rn1[r] + rn2[c] - 2.f * lk[r][c];
                lk[r][c] = fmaxf(M, 0.f) * LKSC;
            }
#pragma unroll
        for (int r = 0; r < 8; ++r) la[r] = (rg + 16*r < n1) ? 0.f : NEG2;
#pragma unroll
        for (int c = 0; c < 8; ++c) {
            lb[c]   = (W4 + 16*c < n2) ? lbv : NEG2;
            mpad[c] = rn2[c] * LKSC;
        }
    }
    const float p1f = (float)(NMAXN - 16 * rmax);
    __syncthreads();   // retire staging view of the union

    switch (cmax) {
        case 4: run_core<4>(lk, la, lb, mpad, p1f, rmax, rg, cg, w, tid, &sm, swred, out, b); break;
        case 5: run_core<5>(lk, la, lb, mpad, p1f, rmax, rg, cg, w, tid, &sm, swred, out, b); break;
        case 6: run_core<6>(lk, la, lb, mpad, p1f, rmax, rg, cg, w, tid, &sm, swred, out, b); break;
        case 7: run_core<7>(lk, la, lb, mpad, p1f, rmax, rg, cg, w, tid, &sm, swred, out, b); break;
        default: run_core<8>(lk, la, lb, mpad, p1f, rmax, rg, cg, w, tid, &sm, swred, out, b); break;
    }
}

extern "C" void kernel_launch(void* const* d_in, const int* in_sizes, int n_in,
                              void* d_out, int out_size, void* d_ws, size_t ws_size,
                              hipStream_t stream) {
    const float* x1  = (const float*)d_in[0];
    const float* x2  = (const float*)d_in[1];
    const int*   sz1 = (const int*)d_in[2];
    const int*   sz2 = (const int*)d_in[3];
    float* out = (float*)d_out;
    int*   ws  = (int*)d_ws;
    hipLaunchKernelGGL(schedule_kernel, dim3(1), dim3(512), 0, stream, sz1, sz2, ws);
    hipLaunchKernelGGL(wasserstein_kernel, dim3(512), dim3(256), 0, stream,
                       x1, x2, sz1, sz2, ws, out);
}

// Round 7
// 2131.190 us; speedup vs baseline: 1.8300x; 1.0004x over previous
//
#include <hip/hip_runtime.h>

#ifndef __has_builtin
#define __has_builtin(x) 0
#endif

__device__ __forceinline__ float fexp2(float x) {
#if __has_builtin(__builtin_amdgcn_exp2f)
    return __builtin_amdgcn_exp2f(x);   // v_exp_f32 (2^x)
#else
    return exp2f(x);
#endif
}
__device__ __forceinline__ float flog2(float x) {
#if __has_builtin(__builtin_amdgcn_logf)
    return __builtin_amdgcn_logf(x);    // v_log_f32 (log2 x)
#else
    return log2f(x);
#endif
}

#define NMAXN 128
#define DD    64
#define MAX_ITERS 500

// -1e5 * log2(e)  (NEG surrogate in log2 domain)
#define NEG2  (-144269.50408889634f)
// -(log2(e) / eps), eps = 1e-3 : logK2 = M * LKSC
#define LKSC  (-1442.6950408889634f)
// -(eps * ln2) : out = acc * OUTSC
#define OUTSC (-6.931471805599453e-4f)

// s_getreg encoding: id | (offset<<6) | ((size-1)<<11)
#define GETREG_ENC(id, off, sz) ((id) | ((off) << 6) | (((sz) - 1) << 11))

struct SmemStage {
    float A[NMAXN * 33];   // set1 chunk [128][32] padded
    float B[NMAXN * 33];   // set2 chunk
    float nA[NMAXN];       // row norms set1
    float nB[NMAXN];       // row norms set2
};
struct SmemSink {
    // [buf][row*5 + w] -> (max,sum)
    float2 part[2][NMAXN * 5];
};
union SmemU {
    SmemStage st;
    SmemSink  sk;
    // occupancy clamp: 56320 B forces exactly 2 blocks/CU (160 KiB / 56.3 KiB)
    // so 512 blocks -> exactly 2 resident per CU, placement-independent.
    float force[14080];
};

// ws layout (ints): [0..511] sched desc-by-work | [512] heavy ctr | [513] fallback
//                   [1024..3071] per-CU {role count | (j+1)<<8} mailboxes
__global__ void schedule_kernel(const int* __restrict__ sz1,
                                const int* __restrict__ sz2,
                                int* __restrict__ ws)
{
    __shared__ int keys[512];
    const int t = threadIdx.x;
    // zero counters+mailbox region [512, 3072)
    for (int i = t; i < 2560; i += 512) ws[512 + i] = 0;
    const int work = ((sz1[t] + 15) >> 4) * ((sz2[t] + 15) >> 4);   // 16..64
    keys[t] = (work << 16) | t;
    __syncthreads();
    for (int kk = 2; kk <= 512; kk <<= 1) {
        for (int j = kk >> 1; j > 0; j >>= 1) {
            int ixj = t ^ j;
            if (ixj > t) {
                int a = keys[t], b = keys[ixj];
                bool asc = ((t & kk) == 0);
                if ((a > b) == asc) { keys[t] = b; keys[ixj] = a; }
            }
            __syncthreads();
        }
    }
    ws[t] = keys[511 - t] & 0xFFFF;   // descending by work
}

// ---------------- Sinkhorn core, templated on col strip count -------------
template<int CMAX>
__device__ __forceinline__ void run_core(
    float (&lk)[8][8], const float (&la)[8], const float (&lb)[8],
    const float (&mpad)[8], float p1f, int rmax,
    int rg, int cg, int w, int tid,
    SmemU* smu, float* swred, float* out, int outb)
{
    float u[8], v[8];
#pragma unroll
    for (int r = 0; r < 8; ++r) u[r] = 0.f;

    for (int k = 0; k < MAX_ITERS; ++k) {
        // ===== phase V: v_j = lb_j - lse_r(lk[r][j] + u[r]) (in-wave) =====
        float mx[CMAX], sc[CMAX];
#pragma unroll
        for (int c = 0; c < CMAX; ++c) mx[c] = lk[0][c] + u[0];
#pragma unroll
        for (int r = 1; r < 4; ++r)
#pragma unroll
            for (int c = 0; c < CMAX; ++c)
                mx[c] = fmaxf(mx[c], lk[r][c] + u[r]);
        if (rmax > 4) {
#pragma unroll
            for (int c = 0; c < CMAX; ++c) mx[c] = fmaxf(mx[c], lk[4][c] + u[4]);
            if (rmax > 5) {
#pragma unroll
                for (int c = 0; c < CMAX; ++c) mx[c] = fmaxf(mx[c], lk[5][c] + u[5]);
                if (rmax > 6) {
#pragma unroll
                    for (int c = 0; c < CMAX; ++c) mx[c] = fmaxf(mx[c], lk[6][c] + u[6]);
                    if (rmax > 7) {
#pragma unroll
                        for (int c = 0; c < CMAX; ++c) mx[c] = fmaxf(mx[c], lk[7][c] + u[7]);
                    }
                }
            }
        }
#pragma unroll
        for (int c = 0; c < CMAX; ++c) {   // reduce over 16 row-groups
            mx[c] = fmaxf(mx[c], __shfl_xor(mx[c], 4));
            mx[c] = fmaxf(mx[c], __shfl_xor(mx[c], 8));
            mx[c] = fmaxf(mx[c], __shfl_xor(mx[c], 16));
            mx[c] = fmaxf(mx[c], __shfl_xor(mx[c], 32));
        }
#pragma unroll
        for (int c = 0; c < CMAX; ++c) sc[c] = fexp2(lk[0][c] + u[0] - mx[c]);
#pragma unroll
        for (int r = 1; r < 4; ++r)
#pragma unroll
            for (int c = 0; c < CMAX; ++c)
                sc[c] += fexp2(lk[r][c] + u[r] - mx[c]);
        if (rmax > 4) {
#pragma unroll
            for (int c = 0; c < CMAX; ++c) sc[c] += fexp2(lk[4][c] + u[4] - mx[c]);
            if (rmax > 5) {
#pragma unroll
                for (int c = 0; c < CMAX; ++c) sc[c] += fexp2(lk[5][c] + u[5] - mx[c]);
                if (rmax > 6) {
#pragma unroll
                    for (int c = 0; c < CMAX; ++c) sc[c] += fexp2(lk[6][c] + u[6] - mx[c]);
                    if (rmax > 7) {
#pragma unroll
                        for (int c = 0; c < CMAX; ++c) sc[c] += fexp2(lk[7][c] + u[7] - mx[c]);
                    }
                }
            }
        }
#pragma unroll
        for (int c = 0; c < CMAX; ++c) {
            sc[c] += __shfl_xor(sc[c], 4);
            sc[c] += __shfl_xor(sc[c], 8);
            sc[c] += __shfl_xor(sc[c], 16);
            sc[c] += __shfl_xor(sc[c], 32);
        }
        if (k == 0 && p1f > 0.5f) {
            // analytic fold of the (128-16*rmax) non-materialized pad rows
#pragma unroll
            for (int c = 0; c < CMAX; ++c) {
                float mm = fmaxf(mx[c], mpad[c]);
                sc[c] = sc[c] * fexp2(mx[c] - mm) + p1f * fexp2(mpad[c] - mm);
                mx[c] = mm;
            }
        }
#pragma unroll
        for (int c = 0; c < CMAX; ++c)
            v[c] = lb[c] - (mx[c] + flog2(sc[c]));

        // ===== phase U: u_r = la_r - lse_c(lk[r][c] + v[c]) =====
        float mr[8], sr[8];
#define U_STRIP(r)                                                          \
        {                                                                   \
            float m_ = lk[r][0] + v[0];                                     \
            _Pragma("unroll")                                               \
            for (int c = 1; c < CMAX; ++c) m_ = fmaxf(m_, lk[r][c] + v[c]); \
            m_ = fmaxf(m_, __shfl_xor(m_, 1));                              \
            m_ = fmaxf(m_, __shfl_xor(m_, 2));                              \
            float s_ = fexp2(lk[r][0] + v[0] - m_);                         \
            _Pragma("unroll")                                               \
            for (int c = 1; c < CMAX; ++c) s_ += fexp2(lk[r][c] + v[c] - m_);\
            s_ += __shfl_xor(s_, 1);                                        \
            s_ += __shfl_xor(s_, 2);                                        \
            mr[r] = m_; sr[r] = s_;                                         \
        }
        U_STRIP(0) U_STRIP(1) U_STRIP(2) U_STRIP(3)
        if (rmax > 4) { U_STRIP(4)
            if (rmax > 5) { U_STRIP(5)
                if (rmax > 6) { U_STRIP(6)
                    if (rmax > 7) { U_STRIP(7) } } } }
#undef U_STRIP

        float2* pb = smu->sk.part[k & 1];
        pb[(rg + 16 * cg) * 5 + w] = make_float2(mr[cg], sr[cg]);
        if (cg + 4 < rmax)
            pb[(rg + 16 * (cg + 4)) * 5 + w] = make_float2(mr[cg + 4], sr[cg + 4]);
        __syncthreads();   // the ONLY barrier per iteration

#define C_STRIP(r)                                                          \
        {                                                                   \
            const float2* pr = &pb[(rg + 16 * (r)) * 5];                    \
            float2 p0 = pr[0], p1 = pr[1], p2 = pr[2], p3 = pr[3];          \
            float m_ = fmaxf(fmaxf(p0.x, p1.x), fmaxf(p2.x, p3.x));         \
            float s_ = p0.y * fexp2(p0.x - m_);                             \
            s_ = fmaf(p1.y, fexp2(p1.x - m_), s_);                          \
            s_ = fmaf(p2.y, fexp2(p2.x - m_), s_);                          \
            s_ = fmaf(p3.y, fexp2(p3.x - m_), s_);                          \
            u[r] = la[r] - (m_ + flog2(s_));                                \
        }
        C_STRIP(0) C_STRIP(1) C_STRIP(2) C_STRIP(3)
        if (rmax > 4) { C_STRIP(4)
            if (rmax > 5) { C_STRIP(5)
                if (rmax > 6) { C_STRIP(6)
                    if (rmax > 7) { C_STRIP(7) } } } }
#undef C_STRIP
    }

    // ---- epilogue: out = OUTSC * sum lk * 2^(lk+u+v) over valid slots ----
    float acc = 0.f;
#define E_STRIP(r)                                                          \
        _Pragma("unroll")                                                   \
        for (int c = 0; c < CMAX; ++c)                                      \
            acc += lk[r][c] * fexp2(lk[r][c] + u[r] + v[c]);
    E_STRIP(0) E_STRIP(1) E_STRIP(2) E_STRIP(3)
    if (rmax > 4) { E_STRIP(4)
        if (rmax > 5) { E_STRIP(5)
            if (rmax > 6) { E_STRIP(6)
                if (rmax > 7) { E_STRIP(7) } } } }
#undef E_STRIP
#pragma unroll
    for (int d = 1; d < 64; d <<= 1) acc += __shfl_xor(acc, d);
    if ((tid & 63) == 0) swred[w] = acc;
    __syncthreads();
    if (tid == 0) out[outb] = (swred[0] + swred[1] + swred[2] + swred[3]) * OUTSC;
}

__global__ __launch_bounds__(256, 2)
void wasserstein_kernel(const float* __restrict__ x1, const float* __restrict__ x2,
                        const int* __restrict__ sz1, const int* __restrict__ sz2,
                        int* __restrict__ ws,
                        float* __restrict__ out)
{
    __shared__ SmemU sm;
    __shared__ int   soff[8];
    __shared__ float swred[4];
    __shared__ int   sb;

    const int tid  = threadIdx.x;
    const int w    = tid >> 6;        // wave 0..3
    const int lane = tid & 63;
    const int rg   = lane >> 2;       // 0..15: rows rg + 16*r
    const int cg   = lane & 3;        // 0..3 : cols w*4+cg + 16*c
    const int W4   = (w << 2) | cg;   // 0..15

    // ---- placement-aware complementary pairing:
    // role-0 block on a CU takes heavy slot j AND publishes j in the per-CU
    // mailbox; its co-resident sibling (role-1) takes slot 511-j. Per-CU work
    // = w[j] + w[511-j] -> tight balance for ANY placement that is 2/CU
    // (guaranteed by the 56.3 KB LDS clamp + 512 blocks = 512 slots).
    if (tid == 0) {
#if __has_builtin(__builtin_amdgcn_s_getreg)
        unsigned hw  = __builtin_amdgcn_s_getreg(GETREG_ENC(4, 0, 32));   // HW_ID
        unsigned xcc = __builtin_amdgcn_s_getreg(GETREG_ENC(20, 0, 32));  // XCC_ID
        unsigned key = ((xcc & 7u) << 8) | ((hw >> 8) & 255u);            // SE|SH|CU
#else
        unsigned key = (unsigned)(blockIdx.x & 2047);
#endif
        int* mb = &ws[1024 + (key & 2047)];
        int prev = atomicAdd(mb, 1);          // low byte: arrival count
        int slot;
        if ((prev & 0xFF) == 0) {
            int j = atomicAdd(&ws[512], 1);   // heavy rank
            atomicAdd(mb, (j + 1) << 8);      // publish j (device-scope)
            slot = j;
        } else {
            int j1 = prev >> 8;               // may already be published
            int t  = 0;
            while (j1 == 0 && t < (1 << 22)) {
                j1 = atomicAdd(mb, 0) >> 8;   // atomic read bypasses caches
                ++t;
            }
            if (j1 != 0) slot = 511 - (j1 - 1);
            else         slot = 511 - atomicAdd(&ws[513], 1);  // never expected
        }
        sb = ws[slot];
    }
    __syncthreads();
    const int b = sb;

    // ---- exclusive prefix sums of sizes (ragged offsets) ----
    int a1 = 0, a2 = 0;
    for (int kk = tid; kk < b; kk += 256) { a1 += sz1[kk]; a2 += sz2[kk]; }
#pragma unroll
    for (int d = 1; d < 64; d <<= 1) {
        a1 += __shfl_xor(a1, d);
        a2 += __shfl_xor(a2, d);
    }
    if (lane == 0) { soff[w] = a1; soff[4 + w] = a2; }
    if (tid < NMAXN) { sm.st.nA[tid] = 0.f; sm.st.nB[tid] = 0.f; }
    __syncthreads();
    const int off1 = soff[0] + soff[1] + soff[2] + soff[3];
    const int off2 = soff[4] + soff[5] + soff[6] + soff[7];
    const int n1 = sz1[b];
    const int n2 = sz2[b];
    const int rmax = (n1 + 15) >> 4;   // 4..8
    const int cmax = (n2 + 15) >> 4;   // 4..8

    // ---- stage sets in D-chunks of 32, accumulate dots + norms ----
    float lk[8][8];
#pragma unroll
    for (int r = 0; r < 8; ++r)
#pragma unroll
        for (int c = 0; c < 8; ++c) lk[r][c] = 0.f;

    const int srow  = tid >> 1;  // 0..127
    const int shalf = tid & 1;   // 16-float half of chunk

    for (int ch = 0; ch < 2; ++ch) {
        const float* p1 = x1 + (size_t)(off1 + srow) * DD + ch * 32 + shalf * 16;
        const float* p2 = x2 + (size_t)(off2 + srow) * DD + ch * 32 + shalf * 16;
        const bool ok1 = srow < n1;
        const bool ok2 = srow < n2;
        float va[16], vb[16];
#pragma unroll
        for (int q = 0; q < 4; ++q) {
            float4 t1 = ok1 ? ((const float4*)p1)[q] : make_float4(0.f, 0.f, 0.f, 0.f);
            float4 t2 = ok2 ? ((const float4*)p2)[q] : make_float4(0.f, 0.f, 0.f, 0.f);
            va[4*q+0] = t1.x; va[4*q+1] = t1.y; va[4*q+2] = t1.z; va[4*q+3] = t1.w;
            vb[4*q+0] = t2.x; vb[4*q+1] = t2.y; vb[4*q+2] = t2.z; vb[4*q+3] = t2.w;
        }
        float s1 = 0.f, s2 = 0.f;
        const int cb = shalf * 16;
#pragma unroll
        for (int q = 0; q < 16; ++q) {
            sm.st.A[srow * 33 + cb + q] = va[q];
            sm.st.B[srow * 33 + cb + q] = vb[q];
            s1 += va[q] * va[q];
            s2 += vb[q] * vb[q];
        }
        s1 += __shfl_xor(s1, 1);
        s2 += __shfl_xor(s2, 1);
        if (shalf == 0) { sm.st.nA[srow] += s1; sm.st.nB[srow] += s2; }
        __syncthreads();
#pragma unroll 2
        for (int d = 0; d < 32; ++d) {
            float av[8], bv[8];
#pragma unroll
            for (int r = 0; r < 8; ++r) av[r] = sm.st.A[(rg + 16*r) * 33 + d];
#pragma unroll
            for (int c = 0; c < 8; ++c) bv[c] = sm.st.B[(W4 + 16*c) * 33 + d];
#pragma unroll
            for (int r = 0; r < 8; ++r)
#pragma unroll
                for (int c = 0; c < 8; ++c)
                    lk[r][c] = fmaf(av[r], bv[c], lk[r][c]);
        }
        __syncthreads();
    }

    // logK2 = -M*log2e/eps, M = ||a||^2+||b||^2-2ab (clamped), + pad/mask data
    float la[8], lb[8], mpad[8];
    const float lbv = flog2((float)n1) - flog2((float)n2);
    {
        float rn1[8], rn2[8];
#pragma unroll
        for (int r = 0; r < 8; ++r) rn1[r] = sm.st.nA[rg + 16*r];
#pragma unroll
        for (int c = 0; c < 8; ++c) rn2[c] = sm.st.nB[W4 + 16*c];
#pragma unroll
        for (int r = 0; r < 8; ++r)
#pragma unroll
            for (int c = 0; c < 8; ++c) {
                float M = rn1[r] + rn2[c] - 2.f * lk[r][c];
                lk[r][c] = fmaxf(M, 0.f) * LKSC;
            }
#pragma unroll
        for (int r = 0; r < 8; ++r) la[r] = (rg + 16*r < n1) ? 0.f : NEG2;
#pragma unroll
        for (int c = 0; c < 8; ++c) {
            lb[c]   = (W4 + 16*c < n2) ? lbv : NEG2;
            mpad[c] = rn2[c] * LKSC;
        }
    }
    const float p1f = (float)(NMAXN - 16 * rmax);
    __syncthreads();   // retire staging view of the union

    switch (cmax) {
        case 4: run_core<4>(lk, la, lb, mpad, p1f, rmax, rg, cg, w, tid, &sm, swred, out, b); break;
        case 5: run_core<5>(lk, la, lb, mpad, p1f, rmax, rg, cg, w, tid, &sm, swred, out, b); break;
        case 6: run_core<6>(lk, la, lb, mpad, p1f, rmax, rg, cg, w, tid, &sm, swred, out, b); break;
        case 7: run_core<7>(lk, la, lb, mpad, p1f, rmax, rg, cg, w, tid, &sm, swred, out, b); break;
        default: run_core<8>(lk, la, lb, mpad, p1f, rmax, rg, cg, w, tid, &sm, swred, out, b); break;
    }
}

extern "C" void kernel_launch(void* const* d_in, const int* in_sizes, int n_in,
                              void* d_out, int out_size, void* d_ws, size_t ws_size,
                              hipStream_t stream) {
    const float* x1  = (const float*)d_in[0];
    const float* x2  = (const float*)d_in[1];
    const int*   sz1 = (const int*)d_in[2];
    const int*   sz2 = (const int*)d_in[3];
    float* out = (float*)d_out;
    int*   ws  = (int*)d_ws;
    hipLaunchKernelGGL(schedule_kernel, dim3(1), dim3(512), 0, stream, sz1, sz2, ws);
    hipLaunchKernelGGL(wasserstein_kernel, dim3(512), dim3(256), 0, stream,
                       x1, x2, sz1, sz2, ws, out);
}